// Round 1
// baseline (431.459 us; speedup 1.0000x reference)
//
#include <hip/hip_runtime.h>

typedef short s16x8 __attribute__((ext_vector_type(8)));
typedef unsigned short u16x8 __attribute__((ext_vector_type(8)));
typedef float f32x16 __attribute__((ext_vector_type(16)));

__device__ __forceinline__ unsigned short f2bf(float f) {
  unsigned u = __float_as_uint(f);
  u += 0x7fffu + ((u >> 16) & 1u);            // round-to-nearest-even
  return (unsigned short)(u >> 16);
}

__device__ __forceinline__ float tanh_fast(float x) {
  float xc = fminf(15.f, fmaxf(-15.f, x));
  float t = __builtin_amdgcn_exp2f(xc * 2.8853900817779268f); // 2*log2(e)
  return (t - 1.f) * __builtin_amdgcn_rcpf(t + 1.f);
}

// ---- prep: pack W (K,N) fp32 -> bf16 MFMA-B-fragment order, via LDS transpose ----
// chunk c = ((tile*KK + kk)*64 + lane), elems j=0..7:
//   value = W[(kk*16 + (lane>>5)*8 + j) * N + tile*32 + (lane&31)]
__global__ __launch_bounds__(256)
void prep_pack(const float* __restrict__ W1, const float* __restrict__ W2,
               const float* __restrict__ W3, unsigned short* __restrict__ ws) {
  __shared__ unsigned short t[64][65];
  const int b = blockIdx.x;
  const float* W; unsigned short* base; int KK, N, tk, tn;
  if (b < 32)      { W = W1; base = ws;          KK = 16; N = 512; tk = b >> 3;       tn = b & 7; }
  else if (b < 96) { int g = b - 32; W = W2; base = ws + 131072; KK = 32; N = 512; tk = g >> 3; tn = g & 7; }
  else             { int g = b - 96; W = W3; base = ws + 393216; KK = 32; N = 128; tk = g >> 1; tn = g & 1; }

  const int tid = threadIdx.x;
  #pragma unroll
  for (int p = 0; p < 16; ++p) {
    int kl = p * 4 + (tid >> 6);
    int nl = tid & 63;
    t[kl][nl] = f2bf(W[(size_t)(tk * 64 + kl) * N + tn * 64 + nl]);
  }
  __syncthreads();

  const int lane = tid & 63, ln31 = lane & 31, khalf = lane >> 5;
  #pragma unroll
  for (int pass = 0; pass < 2; ++pass) {
    int pair = pass * 4 + (tid >> 6);
    int tn_l = pair & 1, kk_l = pair >> 1;
    int tile = tn * 2 + tn_l, kk = tk * 4 + kk_l;
    u16x8 v;
    #pragma unroll
    for (int j = 0; j < 8; ++j)
      v[j] = t[kk_l * 16 + khalf * 8 + j][tn_l * 32 + ln31];
    *(u16x8*)(base + ((size_t)(tile * KK + kk) * 64 + lane) * 8) = v;
  }
}

// h LDS layout: row-major, 16B chunks XOR-swizzled by (row&7).
// short-index(row, ch, wi) = row*512 + ((ch ^ (row&7))*8) + wi
// A-frag addr for lane with fixed row: base ^ (ch*8)  -> 1 VALU per read.
#define ABASE(row) ((row) * 512 + ((row) & 7) * 8)

// M=128 rows/block, 8 waves, each wave computes 128x64 (4m x 2n of 32x32).
// 1 block/CU (128KB LDS), 2 waves/SIMD, 256-reg budget -> real prefetch depth.
__global__ __launch_bounds__(512, 2)
void mlp_limit_kernel(const float* __restrict__ x,
                      const float* __restrict__ b1, const float* __restrict__ b2,
                      const float* __restrict__ b3,
                      const unsigned short* __restrict__ w1p,
                      const unsigned short* __restrict__ w2p,
                      const unsigned short* __restrict__ w3p,
                      float* __restrict__ out) {
  __shared__ __align__(16) unsigned short lds[128 * 512];  // 128KB
  const int tid   = threadIdx.x;
  const int w     = __builtin_amdgcn_readfirstlane(tid >> 6);  // wave id in SGPR
  const int lane  = tid & 63;
  const int ln31  = lane & 31;
  const int khalf = lane >> 5;
  const int m0    = blockIdx.x * 128;

  // ---- stage x tile: 128 rows x 32 chunks (fp32 -> bf16) ----
  #pragma unroll
  for (int c = tid; c < 4096; c += 512) {
    int row = c >> 5, ch = c & 31;
    const float4* src = (const float4*)(x + (size_t)(m0 + row) * 256 + ch * 8);
    float4 f0 = src[0], f1 = src[1];
    u16x8 v;
    v[0] = f2bf(f0.x); v[1] = f2bf(f0.y); v[2] = f2bf(f0.z); v[3] = f2bf(f0.w);
    v[4] = f2bf(f1.x); v[5] = f2bf(f1.y); v[6] = f2bf(f1.z); v[7] = f2bf(f1.w);
    *(u16x8*)&lds[row * 512 + ((ch ^ (row & 7)) * 8)] = v;
  }
  __syncthreads();

  const int abase[4] = { ABASE(ln31), ABASE(ln31 + 32), ABASE(ln31 + 64), ABASE(ln31 + 96) };
  const int ncb    = w * 64;           // this wave's 64 hidden cols
  const int kh32   = khalf * 32;       // epilogue addr helper
  const int khA    = khalf * 8;        // A chunk offset within kk (ch = 2kk+khalf)

  f32x16 acc[4][2];

  // ================= Layer 1: K=256 (16 kk), wave tile 128x64 =================
  #pragma unroll
  for (int mt = 0; mt < 4; ++mt)
    #pragma unroll
    for (int nt = 0; nt < 2; ++nt)
      #pragma unroll
      for (int r = 0; r < 16; ++r) acc[mt][nt][r] = 0.f;
  {
    const s16x8* bp0 = (const s16x8*)w1p + (size_t)((w * 2 + 0) * 16) * 64 + lane;
    const s16x8* bp1 = (const s16x8*)w1p + (size_t)((w * 2 + 1) * 16) * 64 + lane;
    s16x8 a[2][4], b0[2], b1[2];
    b0[0] = bp0[0];  b1[0] = bp1[0];
    b0[1] = bp0[64]; b1[1] = bp1[64];
    #pragma unroll
    for (int mi = 0; mi < 4; ++mi)
      a[0][mi] = *(const s16x8*)&lds[abase[mi] ^ khA];
    #pragma unroll
    for (int kk = 0; kk < 16; ++kk) {
      const int s = kk & 1, d = s ^ 1;
      if (kk + 1 < 16) {
        #pragma unroll
        for (int mi = 0; mi < 4; ++mi)
          a[d][mi] = *(const s16x8*)&lds[abase[mi] ^ ((kk + 1) * 16 + khA)];
      }
      #pragma unroll
      for (int mi = 0; mi < 4; ++mi) {
        acc[mi][0] = __builtin_amdgcn_mfma_f32_32x32x16_bf16(a[s][mi], b0[s], acc[mi][0], 0, 0, 0);
        acc[mi][1] = __builtin_amdgcn_mfma_f32_32x32x16_bf16(a[s][mi], b1[s], acc[mi][1], 0, 0, 0);
      }
      if (kk + 2 < 16) {
        b0[s] = bp0[(kk + 2) * 64];
        b1[s] = bp1[(kk + 2) * 64];
      }
    }
  }
  __syncthreads();    // all x reads done

  #pragma unroll
  for (int nt = 0; nt < 2; ++nt) {
    int hc = ncb + nt * 32 + ln31;
    float bias = b1[hc];
    int wi = hc & 7;
    int e  = (((hc >> 3) * 8) ^ kh32) + wi + khalf * 2048;   // runtime part
    #pragma unroll
    for (int mt = 0; mt < 4; ++mt)
      #pragma unroll
      for (int r = 0; r < 16; ++r) {
        int C = (mt * 32 + (r & 3) + 8 * (r >> 2)) * 512;    // compile-time
        lds[C + (e ^ ((r & 3) * 8))] = f2bf(tanh_fast(acc[mt][nt][r] + bias));
      }
  }
  __syncthreads();

  // ================= Layer 2: K=512 (32 kk), wave tile 128x64 =================
  #pragma unroll
  for (int mt = 0; mt < 4; ++mt)
    #pragma unroll
    for (int nt = 0; nt < 2; ++nt)
      #pragma unroll
      for (int r = 0; r < 16; ++r) acc[mt][nt][r] = 0.f;
  {
    const s16x8* bp0 = (const s16x8*)w2p + (size_t)((w * 2 + 0) * 32) * 64 + lane;
    const s16x8* bp1 = (const s16x8*)w2p + (size_t)((w * 2 + 1) * 32) * 64 + lane;
    s16x8 a[2][4], b0[2], b1[2];
    b0[0] = bp0[0];  b1[0] = bp1[0];
    b0[1] = bp0[64]; b1[1] = bp1[64];
    #pragma unroll
    for (int mi = 0; mi < 4; ++mi)
      a[0][mi] = *(const s16x8*)&lds[abase[mi] ^ khA];
    #pragma unroll
    for (int kk = 0; kk < 32; ++kk) {
      const int s = kk & 1, d = s ^ 1;
      if (kk + 1 < 32) {
        #pragma unroll
        for (int mi = 0; mi < 4; ++mi)
          a[d][mi] = *(const s16x8*)&lds[abase[mi] ^ ((kk + 1) * 16 + khA)];
      }
      #pragma unroll
      for (int mi = 0; mi < 4; ++mi) {
        acc[mi][0] = __builtin_amdgcn_mfma_f32_32x32x16_bf16(a[s][mi], b0[s], acc[mi][0], 0, 0, 0);
        acc[mi][1] = __builtin_amdgcn_mfma_f32_32x32x16_bf16(a[s][mi], b1[s], acc[mi][1], 0, 0, 0);
      }
      if (kk + 2 < 32) {
        b0[s] = bp0[(kk + 2) * 64];
        b1[s] = bp1[(kk + 2) * 64];
      }
    }
  }
  __syncthreads();    // all h1 reads done

  #pragma unroll
  for (int nt = 0; nt < 2; ++nt) {
    int hc = ncb + nt * 32 + ln31;
    float bias = b2[hc];
    int wi = hc & 7;
    int e  = (((hc >> 3) * 8) ^ kh32) + wi + khalf * 2048;
    #pragma unroll
    for (int mt = 0; mt < 4; ++mt)
      #pragma unroll
      for (int r = 0; r < 16; ++r) {
        int C = (mt * 32 + (r & 3) + 8 * (r >> 2)) * 512;
        lds[C + (e ^ ((r & 3) * 8))] = f2bf(tanh_fast(acc[mt][nt][r] + bias));
      }
  }
  __syncthreads();

  // ===== Layer 3: out 128x128; 8 waves as 4m x 2n-of-64; each wave 32x64, K=512 =====
  {
    const int mh  = (w >> 1) * 32;            // row quarter
    const int cg  = (w & 1) * 64;             // col group (2 x 32-col tiles)
    const int ab  = ABASE(mh + ln31);
    f32x16 acc3[2];
    #pragma unroll
    for (int nt = 0; nt < 2; ++nt)
      #pragma unroll
      for (int r = 0; r < 16; ++r) acc3[nt][r] = 0.f;
    const s16x8* bp0 = (const s16x8*)w3p + (size_t)(((w & 1) * 2 + 0) * 32) * 64 + lane;
    const s16x8* bp1 = (const s16x8*)w3p + (size_t)(((w & 1) * 2 + 1) * 32) * 64 + lane;
    s16x8 a[2], b0[2], b1[2];
    b0[0] = bp0[0];  b1[0] = bp1[0];
    b0[1] = bp0[64]; b1[1] = bp1[64];
    a[0] = *(const s16x8*)&lds[ab ^ khA];
    #pragma unroll
    for (int kk = 0; kk < 32; ++kk) {
      const int s = kk & 1, d = s ^ 1;
      if (kk + 1 < 32)
        a[d] = *(const s16x8*)&lds[ab ^ ((kk + 1) * 16 + khA)];
      acc3[0] = __builtin_amdgcn_mfma_f32_32x32x16_bf16(a[s], b0[s], acc3[0], 0, 0, 0);
      acc3[1] = __builtin_amdgcn_mfma_f32_32x32x16_bf16(a[s], b1[s], acc3[1], 0, 0, 0);
      if (kk + 2 < 32) {
        b0[s] = bp0[(kk + 2) * 64];
        b1[s] = bp1[(kk + 2) * 64];
      }
    }
    float bz0 = b3[cg + ln31];
    float bz1 = b3[cg + 32 + ln31];
    #pragma unroll
    for (int r = 0; r < 16; ++r) {
      int m = m0 + mh + (r & 3) + 8 * (r >> 2) + 4 * khalf;
      out[(size_t)m * 128 + cg + ln31]      = acc3[0][r] + bz0;
      out[(size_t)m * 128 + cg + 32 + ln31] = acc3[1][r] + bz1;
    }
  }
}

extern "C" void kernel_launch(void* const* d_in, const int* in_sizes, int n_in,
                              void* d_out, int out_size, void* d_ws, size_t ws_size,
                              hipStream_t stream) {
  const float* x  = (const float*)d_in[0];
  const float* W1 = (const float*)d_in[1];
  const float* b1 = (const float*)d_in[2];
  const float* W2 = (const float*)d_in[3];
  const float* b2 = (const float*)d_in[4];
  const float* W3 = (const float*)d_in[5];
  const float* b3 = (const float*)d_in[6];
  float* out = (float*)d_out;
  unsigned short* ws = (unsigned short*)d_ws;   // 458752 bf16 = 896KB

  hipLaunchKernelGGL(prep_pack, dim3(112), dim3(256), 0, stream, W1, W2, W3, ws);
  hipLaunchKernelGGL(mlp_limit_kernel, dim3(1024), dim3(512), 0, stream,
                     x, b1, b2, b3, ws, ws + 131072, ws + 393216, out);
}

// Round 3
// 342.862 us; speedup vs baseline: 1.2584x; 1.2584x over previous
//
#include <hip/hip_runtime.h>

typedef short s16x8 __attribute__((ext_vector_type(8)));
typedef unsigned short u16x8 __attribute__((ext_vector_type(8)));
typedef float f32x16 __attribute__((ext_vector_type(16)));

__device__ __forceinline__ unsigned short f2bf(float f) {
  unsigned u = __float_as_uint(f);
  u += 0x7fffu + ((u >> 16) & 1u);            // round-to-nearest-even
  return (unsigned short)(u >> 16);
}

__device__ __forceinline__ float tanh_fast(float x) {
  float xc = fminf(15.f, fmaxf(-15.f, x));
  float t = __builtin_amdgcn_exp2f(xc * 2.8853900817779268f); // 2*log2(e)
  return (t - 1.f) * __builtin_amdgcn_rcpf(t + 1.f);
}

// ---- prep: pack W (K,N) fp32 -> bf16 MFMA-B-fragment order, via LDS transpose ----
// chunk c = ((tile*KK + kk)*64 + lane), elems j=0..7:
//   value = W[(kk*16 + (lane>>5)*8 + j) * N + tile*32 + (lane&31)]
__global__ __launch_bounds__(256)
void prep_pack(const float* __restrict__ W1, const float* __restrict__ W2,
               const float* __restrict__ W3, unsigned short* __restrict__ ws) {
  __shared__ unsigned short t[64][65];
  const int b = blockIdx.x;
  const float* W; unsigned short* base; int KK, N, tk, tn;
  if (b < 32)      { W = W1; base = ws;          KK = 16; N = 512; tk = b >> 3;       tn = b & 7; }
  else if (b < 96) { int g = b - 32; W = W2; base = ws + 131072; KK = 32; N = 512; tk = g >> 3; tn = g & 7; }
  else             { int g = b - 96; W = W3; base = ws + 393216; KK = 32; N = 128; tk = g >> 1; tn = g & 1; }

  const int tid = threadIdx.x;
  #pragma unroll
  for (int p = 0; p < 16; ++p) {
    int kl = p * 4 + (tid >> 6);
    int nl = tid & 63;
    t[kl][nl] = f2bf(W[(size_t)(tk * 64 + kl) * N + tn * 64 + nl]);
  }
  __syncthreads();

  const int lane = tid & 63, ln31 = lane & 31, khalf = lane >> 5;
  #pragma unroll
  for (int pass = 0; pass < 2; ++pass) {
    int pair = pass * 4 + (tid >> 6);
    int tn_l = pair & 1, kk_l = pair >> 1;
    int tile = tn * 2 + tn_l, kk = tk * 4 + kk_l;
    u16x8 v;
    #pragma unroll
    for (int j = 0; j < 8; ++j)
      v[j] = t[kk_l * 16 + khalf * 8 + j][tn_l * 32 + ln31];
    *(u16x8*)(base + ((size_t)(tile * KK + kk) * 64 + lane) * 8) = v;
  }
}

// h LDS layout: row-major, 16B chunks XOR-swizzled by (row&7).
// short-index(row, ch, wi) = row*512 + ((ch ^ (row&7))*8) + wi
// A-frag addr for lane with fixed row: base ^ (ch*8)  -> 1 VALU per read.
#define ABASE(row) ((row) * 512 + ((row) & 7) * 8)

// Barrier that preserves LDS ordering (lgkmcnt(0)) but does NOT drain vmcnt,
// so register-destined global loads hoisted above it stay in flight (T4).
#define BAR() asm volatile("s_waitcnt lgkmcnt(0)\n\ts_barrier" ::: "memory")

__global__ __launch_bounds__(512, 4)
void mlp_limit_kernel(const float* __restrict__ x,
                      const float* __restrict__ b1, const float* __restrict__ b2,
                      const float* __restrict__ b3,
                      const unsigned short* __restrict__ w1p,
                      const unsigned short* __restrict__ w2p,
                      const unsigned short* __restrict__ w3p,
                      float* __restrict__ out) {
  __shared__ __align__(16) unsigned short lds[64 * 512];  // 64KB -> 2 blocks/CU
  const int tid   = threadIdx.x;
  const int w     = __builtin_amdgcn_readfirstlane(tid >> 6);  // wave id in SGPR
  const int lane  = tid & 63;
  const int ln31  = lane & 31;
  const int khalf = lane >> 5;
  const int m0    = blockIdx.x * 64;

  // ---- hoist L1 B preloads above x-staging (hide L2 latency under staging) ----
  const s16x8* bpL1_0 = (const s16x8*)w1p + (size_t)((w * 2 + 0) * 16) * 64 + lane;
  const s16x8* bpL1_1 = (const s16x8*)w1p + (size_t)((w * 2 + 1) * 16) * 64 + lane;
  s16x8 bb0[2], bb1[2];
  bb0[0] = bpL1_0[0];  bb1[0] = bpL1_1[0];
  bb0[1] = bpL1_0[64]; bb1[1] = bpL1_1[64];

  // ---- stage x tile: 64 rows x 32 chunks (fp32 -> bf16) ----
  #pragma unroll
  for (int c = tid; c < 2048; c += 512) {
    int row = c >> 5, ch = c & 31;
    const float4* src = (const float4*)(x + (size_t)(m0 + row) * 256 + ch * 8);
    float4 f0 = src[0], f1 = src[1];
    u16x8 v;
    v[0] = f2bf(f0.x); v[1] = f2bf(f0.y); v[2] = f2bf(f0.z); v[3] = f2bf(f0.w);
    v[4] = f2bf(f1.x); v[5] = f2bf(f1.y); v[6] = f2bf(f1.z); v[7] = f2bf(f1.w);
    *(u16x8*)&lds[row * 512 + ((ch ^ (row & 7)) * 8)] = v;
  }
  BAR();

  const int abase0 = ABASE(ln31);
  const int abase1 = ABASE(ln31 + 32);
  const int ncb    = w * 64;           // this wave's 64 hidden cols
  const int kh32   = khalf * 32;       // epilogue addr helper
  const int khA    = khalf * 8;        // A chunk offset within kk (ch = 2kk+khalf)

  f32x16 acc[2][2];

  // ================= Layer 1: K=256 (16 kk), wave tile 64x64 =================
  #pragma unroll
  for (int mt = 0; mt < 2; ++mt)
    #pragma unroll
    for (int nt = 0; nt < 2; ++nt)
      #pragma unroll
      for (int r = 0; r < 16; ++r) acc[mt][nt][r] = 0.f;
  {
    s16x8 a0[2], a1[2];
    a0[0] = *(const s16x8*)&lds[abase0 ^ khA];
    a1[0] = *(const s16x8*)&lds[abase1 ^ khA];
    #pragma unroll
    for (int kk = 0; kk < 16; ++kk) {
      const int s = kk & 1, d = s ^ 1;
      if (kk + 1 < 16) {
        a0[d] = *(const s16x8*)&lds[abase0 ^ ((kk + 1) * 16 + khA)];
        a1[d] = *(const s16x8*)&lds[abase1 ^ ((kk + 1) * 16 + khA)];
      }
      acc[0][0] = __builtin_amdgcn_mfma_f32_32x32x16_bf16(a0[s], bb0[s], acc[0][0], 0, 0, 0);
      acc[0][1] = __builtin_amdgcn_mfma_f32_32x32x16_bf16(a0[s], bb1[s], acc[0][1], 0, 0, 0);
      acc[1][0] = __builtin_amdgcn_mfma_f32_32x32x16_bf16(a1[s], bb0[s], acc[1][0], 0, 0, 0);
      acc[1][1] = __builtin_amdgcn_mfma_f32_32x32x16_bf16(a1[s], bb1[s], acc[1][1], 0, 0, 0);
      if (kk + 2 < 16) {
        bb0[s] = bpL1_0[(kk + 2) * 64];
        bb1[s] = bpL1_1[(kk + 2) * 64];
      }
    }
  }

  // ---- hoist L2 B preloads + ep1 biases before the barrier/epilogue ----
  const s16x8* bpL2_0 = (const s16x8*)w2p + (size_t)((w * 2 + 0) * 32) * 64 + lane;
  const s16x8* bpL2_1 = (const s16x8*)w2p + (size_t)((w * 2 + 1) * 32) * 64 + lane;
  bb0[0] = bpL2_0[0];  bb1[0] = bpL2_1[0];
  bb0[1] = bpL2_0[64]; bb1[1] = bpL2_1[64];
  float bias1[2] = { b1[ncb + ln31], b1[ncb + 32 + ln31] };

  BAR();    // all x reads done

  #pragma unroll
  for (int nt = 0; nt < 2; ++nt) {
    int hc = ncb + nt * 32 + ln31;
    int wi = hc & 7;
    int e  = (((hc >> 3) * 8) ^ kh32) + wi + khalf * 2048;   // runtime part
    #pragma unroll
    for (int mt = 0; mt < 2; ++mt)
      #pragma unroll
      for (int r = 0; r < 16; ++r) {
        int C = (mt * 32 + (r & 3) + 8 * (r >> 2)) * 512;    // compile-time
        lds[C + (e ^ ((r & 3) * 8))] = f2bf(tanh_fast(acc[mt][nt][r] + bias1[nt]));
      }
  }
  BAR();

  // ================= Layer 2: K=512 (32 kk), wave tile 64x64 =================
  #pragma unroll
  for (int mt = 0; mt < 2; ++mt)
    #pragma unroll
    for (int nt = 0; nt < 2; ++nt)
      #pragma unroll
      for (int r = 0; r < 16; ++r) acc[mt][nt][r] = 0.f;
  {
    s16x8 a0[2], a1[2];
    a0[0] = *(const s16x8*)&lds[abase0 ^ khA];
    a1[0] = *(const s16x8*)&lds[abase1 ^ khA];
    #pragma unroll
    for (int kk = 0; kk < 32; ++kk) {
      const int s = kk & 1, d = s ^ 1;
      if (kk + 1 < 32) {
        a0[d] = *(const s16x8*)&lds[abase0 ^ ((kk + 1) * 16 + khA)];
        a1[d] = *(const s16x8*)&lds[abase1 ^ ((kk + 1) * 16 + khA)];
      }
      acc[0][0] = __builtin_amdgcn_mfma_f32_32x32x16_bf16(a0[s], bb0[s], acc[0][0], 0, 0, 0);
      acc[0][1] = __builtin_amdgcn_mfma_f32_32x32x16_bf16(a0[s], bb1[s], acc[0][1], 0, 0, 0);
      acc[1][0] = __builtin_amdgcn_mfma_f32_32x32x16_bf16(a1[s], bb0[s], acc[1][0], 0, 0, 0);
      acc[1][1] = __builtin_amdgcn_mfma_f32_32x32x16_bf16(a1[s], bb1[s], acc[1][1], 0, 0, 0);
      if (kk + 2 < 32) {
        bb0[s] = bpL2_0[(kk + 2) * 64];
        bb1[s] = bpL2_1[(kk + 2) * 64];
      }
    }
  }

  // ---- hoist L3 B preloads (depth-3 ring) + biases before ep2 ----
  const int t3 = w & 3;                     // L3 col tile
  const int mh = (w >> 2) * 32;             // L3 row half
  const s16x8* bpL3 = (const s16x8*)w3p + (size_t)(t3 * 32) * 64 + lane;
  s16x8 b3r[3];
  b3r[0] = bpL3[0]; b3r[1] = bpL3[64]; b3r[2] = bpL3[128];
  float bias2[2] = { b2[ncb + ln31], b2[ncb + 32 + ln31] };
  float bz = b3[t3 * 32 + ln31];

  BAR();    // all h1 reads done

  #pragma unroll
  for (int nt = 0; nt < 2; ++nt) {
    int hc = ncb + nt * 32 + ln31;
    int wi = hc & 7;
    int e  = (((hc >> 3) * 8) ^ kh32) + wi + khalf * 2048;
    #pragma unroll
    for (int mt = 0; mt < 2; ++mt)
      #pragma unroll
      for (int r = 0; r < 16; ++r) {
        int C = (mt * 32 + (r & 3) + 8 * (r >> 2)) * 512;
        lds[C + (e ^ ((r & 3) * 8))] = f2bf(tanh_fast(acc[mt][nt][r] + bias2[nt]));
      }
  }
  BAR();

  // ===== Layer 3: out 64x128; 8 waves as 2m x 4n of 32x32 tiles, K=512 =====
  // Depth-3 rings on both A (LDS, ~120cyc) and B (L2, ~200-400cyc): the
  // single-acc chain was serially latency-bound at depth 2.
  {
    const int ab = ABASE(mh + ln31);
    f32x16 acc3;
    #pragma unroll
    for (int r = 0; r < 16; ++r) acc3[r] = 0.f;
    s16x8 a3[3];
    a3[0] = *(const s16x8*)&lds[ab ^ (0 * 16 + khA)];
    a3[1] = *(const s16x8*)&lds[ab ^ (1 * 16 + khA)];
    a3[2] = *(const s16x8*)&lds[ab ^ (2 * 16 + khA)];
    #pragma unroll
    for (int kk = 0; kk < 32; ++kk) {
      const int s = kk % 3;               // static: loop fully unrolled
      acc3 = __builtin_amdgcn_mfma_f32_32x32x16_bf16(a3[s], b3r[s], acc3, 0, 0, 0);
      if (kk + 3 < 32) {
        a3[s]  = *(const s16x8*)&lds[ab ^ ((kk + 3) * 16 + khA)];
        b3r[s] = bpL3[(kk + 3) * 64];
      }
    }
    #pragma unroll
    for (int r = 0; r < 16; ++r) {
      int m = m0 + mh + (r & 3) + 8 * (r >> 2) + 4 * khalf;
      out[(size_t)m * 128 + t3 * 32 + ln31] = acc3[r] + bz;
    }
  }
}

extern "C" void kernel_launch(void* const* d_in, const int* in_sizes, int n_in,
                              void* d_out, int out_size, void* d_ws, size_t ws_size,
                              hipStream_t stream) {
  const float* x  = (const float*)d_in[0];
  const float* W1 = (const float*)d_in[1];
  const float* b1 = (const float*)d_in[2];
  const float* W2 = (const float*)d_in[3];
  const float* b2 = (const float*)d_in[4];
  const float* W3 = (const float*)d_in[5];
  const float* b3 = (const float*)d_in[6];
  float* out = (float*)d_out;
  unsigned short* ws = (unsigned short*)d_ws;   // 458752 bf16 = 896KB

  hipLaunchKernelGGL(prep_pack, dim3(112), dim3(256), 0, stream, W1, W2, W3, ws);
  hipLaunchKernelGGL(mlp_limit_kernel, dim3(2048), dim3(512), 0, stream,
                     x, b1, b2, b3, ws, ws + 131072, ws + 393216, out);
}